// Round 14
// baseline (2157.641 us; speedup 1.0000x reference)
//
#include <hip/hip_runtime.h>

// 2-layer LSTM (B=256, T=512, D=64, H=256) + FC(256->4).
// Round-14: two-stream pipelining with JUST-IN-TIME staging rotation.
// 16 supergroups x 8 blocks; each block serves two batch groups A,B with the
// same register-resident weights. Iter s phases:
//   stageA(s) | bar1 | MFMA_A | bar2 | prefB-issue, guard, act_A+storeA,
//   stageB(s) | bar3 (post cflag=s+1) | MFMA_B | bar4 | prefA-issue(s+1),
//   act_B+storeB
// Stream A's packets aged by phase B of iter s-1; B's by phase A of iter s
// (~0.5-0.8us) before validation -> L3 visibility hidden (r13 staged both at
// superstep end: B aged ~0 -> full stall; that was the regression).
// Protocol identical to r12/r13: u64 {epoch32|2xf16} packets, relaxed
// agent-scope atomics, ring-4, slack-2 cflag guard (tgt=s-2), epoch-0 memset
// = h(-1)=0. Blocks 0-3: L0 quadrant q; 4-7: L1 quadrant q; systolic skew.

#define TT 512
#define HH 256
#define DD 64

typedef __attribute__((ext_vector_type(2))) _Float16 h2t;
typedef __attribute__((ext_vector_type(8))) _Float16 f16x8;
typedef __attribute__((ext_vector_type(4))) float f32x4;
typedef unsigned long long u64;
typedef unsigned u32;

__device__ __forceinline__ u32 pkh(float x, float y) {
    h2t h; h.x = (_Float16)x; h.y = (_Float16)y;
    return __builtin_bit_cast(u32, h);
}
__device__ __forceinline__ float sigf(float x) { return 1.f / (1.f + __expf(-x)); }
__device__ __forceinline__ float tanhf_(float x) {
    float e = __expf(2.f * x);
    return 1.f - 2.f / (e + 1.f);   // safe at +/-inf
}
__device__ __forceinline__ f16x8 ld8(const float* p) {
    float4 u = ((const float4*)p)[0];
    float4 v = ((const float4*)p)[1];
    f16x8 r = {(_Float16)u.x, (_Float16)u.y, (_Float16)u.z, (_Float16)u.w,
               (_Float16)v.x, (_Float16)v.y, (_Float16)v.z, (_Float16)v.w};
    return r;
}
__device__ __forceinline__ u32 ld32(const u32* p) {
    return __hip_atomic_load(p, __ATOMIC_RELAXED, __HIP_MEMORY_SCOPE_AGENT);
}
__device__ __forceinline__ void st32(u32* p, u32 v) {
    __hip_atomic_store(p, v, __ATOMIC_RELAXED, __HIP_MEMORY_SCOPE_AGENT);
}
__device__ __forceinline__ u64 ld64(const u64* p) {
    return __hip_atomic_load(p, __ATOMIC_RELAXED, __HIP_MEMORY_SCOPE_AGENT);
}
__device__ __forceinline__ void st64(u64* p, u64 v) {
    __hip_atomic_store(p, v, __ATOMIC_RELAXED, __HIP_MEMORY_SCOPE_AGENT);
}

__global__ __launch_bounds__(512, 2) void lstm_persist(
    const float* __restrict__ x,
    const float* __restrict__ Wih0, const float* __restrict__ Whh0,
    const float* __restrict__ bih0, const float* __restrict__ bhh0,
    const float* __restrict__ Wih1, const float* __restrict__ Whh1,
    const float* __restrict__ bih1, const float* __restrict__ bhh1,
    const float* __restrict__ fcW, const float* __restrict__ fcb,
    float* __restrict__ out,
    u64* h0ring, u64* h1ring, u32* cflagsA)
{
    __shared__ __align__(16) _Float16 sBA[9216];     // stream A: 64 ch x 144 halves
    __shared__ __align__(16) _Float16 sBB[9216];     // stream B
    __shared__ __align__(16) float p2A[2][8][276];   // k-split partials, A
    __shared__ __align__(16) float p2B[2][8][276];   // B

    const int tid  = threadIdx.x;
    const int sg   = blockIdx.x & 15;     // supergroup
    const int role = blockIdx.x >> 4;     // 0..7
    const bool isL1 = role >= 4;
    const int q = role & 3;
    const int gA = sg * 2, gB = sg * 2 + 1;
    const int batch0A = gA * 8, batch0B = gB * 8;
    u64* rA0 = h0ring + (size_t)gA * 4096;   // [slot4][q4][j8][hp32]
    u64* rA1 = h1ring + (size_t)gA * 4096;
    u64* rB0 = h0ring + (size_t)gB * 4096;
    u64* rB1 = h1ring + (size_t)gB * 4096;
    u32* cflag = cflagsA + (size_t)sg * 16;

    const int lane = tid & 63, w = tid >> 6;
    const int mw = w & 3, kh = w >> 2;
    const int bcol = lane & 15, kc = lane >> 4;

    // ---- A-fragment rows: wave mw owns gate mw; tiles ti=0..3 (r12 layout) ----
    const int R0 = mw * 256 + 64 * q + (lane & 15);
    const int R1 = R0 + 16, R2 = R0 + 32, R3 = R0 + 48;

#define DECL_TI(ti) f16x8 A##ti##_0={},A##ti##_1={},A##ti##_2={},A##ti##_3={}, \
                          A##ti##_4={},A##ti##_5={},A##ti##_6={},A##ti##_7={};
    DECL_TI(0) DECL_TI(1) DECL_TI(2) DECL_TI(3)
#undef DECL_TI

    if (isL1) {
#define LDA1(ti,j) { int k_ = (kh*8+(j))*32 + kc*8;                          \
        A##ti##_##j = ld8(k_ < 256 ? Wih1 + (size_t)R##ti*256 + k_           \
                                   : Whh1 + (size_t)R##ti*256 + (k_-256)); }
#define LDA1T(ti) LDA1(ti,0) LDA1(ti,1) LDA1(ti,2) LDA1(ti,3) \
                  LDA1(ti,4) LDA1(ti,5) LDA1(ti,6) LDA1(ti,7)
        LDA1T(0) LDA1T(1) LDA1T(2) LDA1T(3)
#undef LDA1T
#undef LDA1
    } else {
#define LDA0(ti,j) { int k_ = (kh*5+(j))*32 + kc*8;                          \
        A##ti##_##j = ld8(k_ < 64 ? Wih0 + (size_t)R##ti*64 + k_             \
                                  : Whh0 + (size_t)R##ti*256 + (k_-64)); }
#define LDA0T(ti) LDA0(ti,0) LDA0(ti,1) LDA0(ti,2) LDA0(ti,3) LDA0(ti,4)
        LDA0T(0) LDA0T(1) LDA0T(2) LDA0T(3)
#undef LDA0T
#undef LDA0
    }

    // ---- activation duty: thread (lane = h-idx in quadrant, w = batch) ----
    const float* bA = isL1 ? bih1 : bih0;
    const float* bB = isL1 ? bhh1 : bhh0;
    const float bz0 = bA[      64*q + lane] + bB[      64*q + lane];
    const float bz1 = bA[256 + 64*q + lane] + bB[256 + 64*q + lane];
    const float bz2 = bA[512 + 64*q + lane] + bB[512 + 64*q + lane];
    const float bz3 = bA[768 + 64*q + lane] + bB[768 + 64*q + lane];
    float cstA = 0.f, cstB = 0.f;

    u32* const sBuA = (u32*)sBA;
    u32* const sBuB = (u32*)sBB;
    for (int i = tid; i < 4608; i += 512) { sBuA[i] = 0; sBuB[i] = 0; }
    __syncthreads();   // zero-fill (pad rows + h(-1)=0) complete

// MFMA over one stream's sB into its part2
#define MST(j, ktb, SBP) { const f16x8 Bf = *(const f16x8*)((SBP) + (((ktb)+(j))*4 + kc)*144 + bcol*8); \
    C0 = __builtin_amdgcn_mfma_f32_16x16x32_f16(A0_##j, Bf, C0, 0,0,0); \
    C1 = __builtin_amdgcn_mfma_f32_16x16x32_f16(A1_##j, Bf, C1, 0,0,0); \
    C2 = __builtin_amdgcn_mfma_f32_16x16x32_f16(A2_##j, Bf, C2, 0,0,0); \
    C3 = __builtin_amdgcn_mfma_f32_16x16x32_f16(A3_##j, Bf, C3, 0,0,0); }
#define MFMA_STREAM(SBP, P2) do {                                            \
    f32x4 C0={0,0,0,0},C1={0,0,0,0},C2={0,0,0,0},C3={0,0,0,0};               \
    if (isL1) { const int ktb = kh * 8;                                      \
        MST(0,ktb,SBP) MST(1,ktb,SBP) MST(2,ktb,SBP) MST(3,ktb,SBP)          \
        MST(4,ktb,SBP) MST(5,ktb,SBP) MST(6,ktb,SBP) MST(7,ktb,SBP)          \
    } else { const int ktb = kh * 5;                                         \
        MST(0,ktb,SBP) MST(1,ktb,SBP) MST(2,ktb,SBP) MST(3,ktb,SBP)          \
        MST(4,ktb,SBP) }                                                     \
    if (bcol < 8) {                                                          \
        *(f32x4*)&P2[kh][bcol][mw*64 +  0 + kc*4] = C0;                      \
        *(f32x4*)&P2[kh][bcol][mw*64 + 16 + kc*4] = C1;                      \
        *(f32x4*)&P2[kh][bcol][mw*64 + 32 + kc*4] = C2;                      \
        *(f32x4*)&P2[kh][bcol][mw*64 + 48 + kc*4] = C3;                      \
    } } while (0)

// activation + ring store for one stream (epoch s+1 packets)
#define ACT_STREAM(P2, CST, RBASE) do {                                      \
    float s0 = P2[0][w][      lane] + P2[1][w][      lane] + bz0;            \
    float s1 = P2[0][w][ 64 + lane] + P2[1][w][ 64 + lane] + bz1;            \
    float s2 = P2[0][w][128 + lane] + P2[1][w][128 + lane] + bz2;            \
    float s3 = P2[0][w][192 + lane] + P2[1][w][192 + lane] + bz3;            \
    float fi = sigf(s0), ff = sigf(s1), fg = tanhf_(s2), fo = sigf(s3);      \
    CST = ff * CST + fi * fg;                                                \
    float h = fo * tanhf_(CST);                                              \
    float hn = __shfl_down(h, 1);                                            \
    u32 hw = pkh(h, hn);                                                     \
    if (!(lane & 1)) {                                                       \
        u64 v = ((u64)(u32)(s + 1) << 32) | (u64)hw;                         \
        st64((RBASE) + q * 256 + w * 32 + (lane >> 1), v);                   \
    } } while (0)

// retry until epochs match, then write one stream's sB (h parts)
#define VALIDATE_WRITE(SBU, V0, V1, V2, V3, A00, A01, A10, A11, E0, E1)      \
    for (;;) {                                                               \
        bool k0 = ((u32)((V0) >> 32) == (E0));                               \
        bool k1 = ((u32)((V1) >> 32) == (E0));                               \
        bool k2 = !isL1 || ((u32)((V2) >> 32) == (E1));                      \
        bool k3 = !isL1 || ((u32)((V3) >> 32) == (E1));                      \
        if (k0 & k1 & k2 & k3) break;                                        \
        if (!k0) (V0) = ld64(A00);                                           \
        if (!k1) (V1) = ld64(A01);                                           \
        if (isL1) { if (!k2) (V2) = ld64(A10);                               \
                    if (!k3) (V3) = ld64(A11); }                             \
    }                                                                        \
    {                                                                        \
        const int cb0 = isL1 ? 0 : 8;                                        \
        (SBU)[(cb0 + (n0 >> 2)) * 72 + jj0 * 4 + (n0 & 3)] = (u32)(V0);      \
        (SBU)[(cb0 + (n0 >> 2)) * 72 + jj1 * 4 + (n0 & 3)] = (u32)(V1);      \
        if (isL1) {                                                          \
            (SBU)[(32 + (n0 >> 2)) * 72 + jj0 * 4 + (n0 & 3)] = (u32)(V2);   \
            (SBU)[(32 + (n0 >> 2)) * 72 + jj1 * 4 + (n0 & 3)] = (u32)(V3);   \
        }                                                                    \
    }

    const int n0 = tid & 127;
    const int jj0 = tid >> 7, jj1 = 4 + jj0;
    const size_t qoff = (size_t)((n0 >> 5) << 8) + (n0 & 31);

    u64 pA0 = 0, pA1 = 0, pA2 = 0, pA3 = 0;   // prefetched packets (A, next iter)
    u64 pB0 = 0, pB1 = 0, pB2 = 0, pB3 = 0;   // prefetched packets (B, this iter)
    float4 pAx = {0,0,0,0}, pBx = {0,0,0,0};  // prefetched x rows

    for (int s = 0; s <= TT; ++s) {
        const bool act_ = isL1 ? (s >= 1) : (s < TT);
        const bool stgS = act_;               // stage step s this iter
        const u32 e0 = (u32)s;
        const u32 e1 = (s >= 2) ? (u32)s : 0u;

        // ---- PHASE A: stage A(step s) -- packets aged by phase B of s-1 ----
        if (stgS) {
            const u64* b0 = rA0 + (size_t)((s - 1) & 3) * 1024 + qoff;
            const u64 *a00 = b0 + jj0 * 32, *a01 = b0 + jj1 * 32;
            const u64 *a10 = nullptr, *a11 = nullptr;
            if (isL1) {
                const u64* b1 = rA1 + (size_t)((s + 2) & 3) * 1024 + qoff;
                a10 = b1 + jj0 * 32; a11 = b1 + jj1 * 32;
            }
            u64 v0, v1, v2 = 0, v3 = 0;
            if (s > 0) { v0 = pA0; v1 = pA1; v2 = pA2; v3 = pA3; }
            else { v0 = ld64(a00); v1 = ld64(a01);
                   if (isL1) { v2 = ld64(a10); v3 = ld64(a11); } }
            VALIDATE_WRITE(sBuA, v0, v1, v2, v3, a00, a01, a10, a11, e0, e1)
            if (!isL1 && tid >= 256 && tid < 384) {
                int t2 = tid - 256, j = t2 >> 4, c = t2 & 15;
                float4 xv = (s > 0) ? pAx
                    : ((const float4*)(x + (size_t)(batch0A + j) * TT * DD))[c];
                int bidx = (c >> 1) * 72 + j * 4 + 2 * (c & 1);
                sBuA[bidx]     = pkh(xv.x, xv.y);
                sBuA[bidx + 1] = pkh(xv.z, xv.w);
            }
        }
        __syncthreads();                      // bar1: sBA staged
        if (act_) MFMA_STREAM(sBA, p2A);
        __syncthreads();                      // bar2: p2A ready, sBA reads done

        // guard preload + B packet prefetch (ride under act_A)
        u32 cpre = 0u;
        if (act_ && lane < 8) cpre = ld32(&cflag[lane]);
        const u64 *aB00 = nullptr, *aB01 = nullptr, *aB10 = nullptr, *aB11 = nullptr;
        if (stgS) {
            const u64* b0 = rB0 + (size_t)((s - 1) & 3) * 1024 + qoff;
            aB00 = b0 + jj0 * 32; aB01 = b0 + jj1 * 32;
            pB0 = ld64(aB00); pB1 = ld64(aB01);
            if (isL1) {
                const u64* b1 = rB1 + (size_t)((s + 2) & 3) * 1024 + qoff;
                aB10 = b1 + jj0 * 32; aB11 = b1 + jj1 * 32;
                pB2 = ld64(aB10); pB3 = ld64(aB11);
            }
        }

        if (act_) {
            // ring-overwrite guard: all blocks staged step s-3 (value >= s-2)
            const int tgt = s - 2;
            while (!__all(lane >= 8 || (int)cpre >= tgt)) {
                __builtin_amdgcn_s_sleep(1);
                if (lane < 8) cpre = ld32(&cflag[lane]);
            }
            ACT_STREAM(p2A, cstA,
                       (isL1 ? rA1 + (size_t)((s - 1) & 3) * 1024
                             : rA0 + (size_t)(s & 3) * 1024));
        }

        // ---- stage B(step s) -- packets aged by phase A of this iter ----
        if (stgS) {
            VALIDATE_WRITE(sBuB, pB0, pB1, pB2, pB3, aB00, aB01, aB10, aB11, e0, e1)
            if (!isL1 && tid >= 384) {
                int t2 = tid - 384, j = t2 >> 4, c = t2 & 15;
                float4 xv = (s > 0) ? pBx
                    : ((const float4*)(x + (size_t)(batch0B + j) * TT * DD))[c];
                int bidx = (c >> 1) * 72 + j * 4 + 2 * (c & 1);
                sBuB[bidx]     = pkh(xv.x, xv.y);
                sBuB[bidx + 1] = pkh(xv.z, xv.w);
            }
        }
        __syncthreads();                      // bar3: sBB staged (A staged earlier)
        if (tid == 0) st32(&cflag[role], (u32)(s + 1));   // staged step s (A+B)
        if (act_) MFMA_STREAM(sBB, p2B);
        __syncthreads();                      // bar4: p2B ready, sBB reads done

        // prefetch A packets + both x rows for iter s+1 (ride under act_B)
        {
            const int sn = s + 1;
            const bool stgN = isL1 ? (sn <= TT) : (sn < TT);
            if (stgN) {
                const u64* b0 = rA0 + (size_t)((sn - 1) & 3) * 1024 + qoff;
                pA0 = ld64(b0 + jj0 * 32); pA1 = ld64(b0 + jj1 * 32);
                if (isL1) {
                    const u64* b1 = rA1 + (size_t)((sn + 2) & 3) * 1024 + qoff;
                    pA2 = ld64(b1 + jj0 * 32); pA3 = ld64(b1 + jj1 * 32);
                } else {
                    if (tid >= 256 && tid < 384) {
                        int t2 = tid - 256, j = t2 >> 4, c = t2 & 15;
                        pAx = ((const float4*)(
                            x + ((size_t)(batch0A + j) * TT + sn) * DD))[c];
                    } else if (tid >= 384) {
                        int t2 = tid - 384, j = t2 >> 4, c = t2 & 15;
                        pBx = ((const float4*)(
                            x + ((size_t)(batch0B + j) * TT + sn) * DD))[c];
                    }
                }
            }
        }

        if (act_) {
            ACT_STREAM(p2B, cstB,
                       (isL1 ? rB1 + (size_t)((s - 1) & 3) * 1024
                             : rB0 + (size_t)(s & 3) * 1024));
        }
    }
#undef MST
#undef MFMA_STREAM
#undef ACT_STREAM
#undef VALIDATE_WRITE

    // ---- final FC on h1(TT-1) for both streams: ring slot 3, epoch TT+1 ----
    if (isL1 && q == 0) {
        const u32 ef = (u32)(TT + 1);
        const u64* bAp = rA1 + 3 * 1024 + qoff;
        const u64* bBp = rB1 + 3 * 1024 + qoff;
        const u64 *a0 = bAp + jj0*32, *a1 = bAp + jj1*32;
        const u64 *a2 = bBp + jj0*32, *a3 = bBp + jj1*32;
        u64 v0 = ld64(a0), v1 = ld64(a1), v2 = ld64(a2), v3 = ld64(a3);
        for (;;) {
            bool k0 = ((u32)(v0 >> 32) == ef), k1 = ((u32)(v1 >> 32) == ef);
            bool k2 = ((u32)(v2 >> 32) == ef), k3 = ((u32)(v3 >> 32) == ef);
            if (k0 & k1 & k2 & k3) break;
            if (!k0) v0 = ld64(a0);  if (!k1) v1 = ld64(a1);
            if (!k2) v2 = ld64(a2);  if (!k3) v3 = ld64(a3);
        }
        sBuA[jj0 * 128 + n0] = (u32)v0;   // flat [batch][128 u32] per stream
        sBuA[jj1 * 128 + n0] = (u32)v1;
        sBuB[jj0 * 128 + n0] = (u32)v2;
        sBuB[jj1 * 128 + n0] = (u32)v3;
        __syncthreads();
        const int j = tid >> 5;              // 0..15 (A: 0-7, B: 8-15)
        const int l2 = tid & 31, o = l2 >> 3, kk = l2 & 7;
        const _Float16* hsrc = (j < 8) ? (sBA + j * 256) : (sBB + (j - 8) * 256);
        float ssum = 0.f;
#pragma unroll
        for (int m = 0; m < 32; ++m) {
            int k = kk * 32 + m;
            ssum += (float)hsrc[k] * fcW[o * HH + k];
        }
        ssum += __shfl_down(ssum, 4);
        ssum += __shfl_down(ssum, 2);
        ssum += __shfl_down(ssum, 1);
        if (kk == 0) out[(sg * 16 + j) * 4 + o] = ssum + fcb[o];
    }
}

extern "C" void kernel_launch(void* const* d_in, const int* in_sizes, int n_in,
                              void* d_out, int out_size, void* d_ws, size_t ws_size,
                              hipStream_t stream)
{
    (void)in_sizes; (void)n_in; (void)out_size; (void)ws_size;
    const float* x    = (const float*)d_in[0];
    const float* Wih0 = (const float*)d_in[1];
    const float* Whh0 = (const float*)d_in[2];
    const float* bih0 = (const float*)d_in[3];
    const float* bhh0 = (const float*)d_in[4];
    const float* Wih1 = (const float*)d_in[5];
    const float* Whh1 = (const float*)d_in[6];
    const float* bih1 = (const float*)d_in[7];
    const float* bhh1 = (const float*)d_in[8];
    const float* fcW  = (const float*)d_in[9];
    const float* fcb  = (const float*)d_in[10];
    float* out = (float*)d_out;

    // ws: h0ring 1MB (32 grp x 4 slot x 1024 u64) | h1ring 1MB | cflags 2KB
    u64* h0ring = (u64*)d_ws;
    u64* h1ring = (u64*)((char*)d_ws + 1048576);
    u32* cflags = (u32*)((char*)d_ws + 2097152);

    hipMemsetAsync(d_ws, 0, 2097152 + 2048, stream);   // epoch 0 == h(-1)=0

    lstm_persist<<<dim3(128), dim3(512), 0, stream>>>(
        x, Wih0, Whh0, bih0, bhh0, Wih1, Whh1, bih1, bhh1, fcW, fcb, out,
        h0ring, h1ring, cflags);
}

// Round 15
// 1722.732 us; speedup vs baseline: 1.2525x; 1.2525x over previous
//
#include <hip/hip_runtime.h>

// 2-layer LSTM (B=256, T=512, D=64, H=256) + FC(256->4).
// 32 groups x 8 blocks; blocks 0-3: L0 quadrant q, 4-7: L1 quadrant q.
// Round-15 (base r12 = best 1319us):
//  * SKEW-2: at iter s, L0 computes h0(s), L1 computes h1(s-2). L1's h0
//    operand is 2 iters old -> always visible (no wait on L0->L1 edge).
//  * FRESH-LAST iter split: bar_A | issue fresh loads (parked) | stage_old
//    (L1: h0(s-2); L0: x(s)) | bar_B | MFMA_old (old-operand K-chunks) |
//    validate fresh (aged ~0.4us by now) | bar_C | MFMA_fresh | bar_D |
//    guard+act+ring-store. Exposed wait = visibility - aging.
//  * Ring-8 both layers; epoch(t)=t+1; guard tgt=s-5 (slot s&7 overwrites
//    h(s-8), latest reader is L1's old-stage at iter s-6 -> flag >= s-5).
// Protocol primitives unchanged: u64 {epoch32|2xf16} packets, relaxed
// agent-scope atomics, slack guard via cflags, epoch-0 memset = h(-1)=0.

#define TT 512
#define HH 256
#define DD 64

typedef __attribute__((ext_vector_type(2))) _Float16 h2t;
typedef __attribute__((ext_vector_type(8))) _Float16 f16x8;
typedef __attribute__((ext_vector_type(4))) float f32x4;
typedef unsigned long long u64;
typedef unsigned u32;

__device__ __forceinline__ u32 pkh(float x, float y) {
    h2t h; h.x = (_Float16)x; h.y = (_Float16)y;
    return __builtin_bit_cast(u32, h);
}
__device__ __forceinline__ float sigf(float x) { return 1.f / (1.f + __expf(-x)); }
__device__ __forceinline__ float tanhf_(float x) {
    float e = __expf(2.f * x);
    return 1.f - 2.f / (e + 1.f);   // safe at +/-inf
}
__device__ __forceinline__ f16x8 ld8(const float* p) {
    float4 u = ((const float4*)p)[0];
    float4 v = ((const float4*)p)[1];
    f16x8 r = {(_Float16)u.x, (_Float16)u.y, (_Float16)u.z, (_Float16)u.w,
               (_Float16)v.x, (_Float16)v.y, (_Float16)v.z, (_Float16)v.w};
    return r;
}
__device__ __forceinline__ u32 ld32(const u32* p) {
    return __hip_atomic_load(p, __ATOMIC_RELAXED, __HIP_MEMORY_SCOPE_AGENT);
}
__device__ __forceinline__ void st32(u32* p, u32 v) {
    __hip_atomic_store(p, v, __ATOMIC_RELAXED, __HIP_MEMORY_SCOPE_AGENT);
}
__device__ __forceinline__ u64 ld64(const u64* p) {
    return __hip_atomic_load(p, __ATOMIC_RELAXED, __HIP_MEMORY_SCOPE_AGENT);
}
__device__ __forceinline__ void st64(u64* p, u64 v) {
    __hip_atomic_store(p, v, __ATOMIC_RELAXED, __HIP_MEMORY_SCOPE_AGENT);
}

__global__ __launch_bounds__(512, 2) void lstm_persist(
    const float* __restrict__ x,
    const float* __restrict__ Wih0, const float* __restrict__ Whh0,
    const float* __restrict__ bih0, const float* __restrict__ bhh0,
    const float* __restrict__ Wih1, const float* __restrict__ Whh1,
    const float* __restrict__ bih1, const float* __restrict__ bhh1,
    const float* __restrict__ fcW, const float* __restrict__ fcb,
    float* __restrict__ out,
    u64* h0ring, u64* h1ring, u32* cflagsA)
{
    __shared__ __align__(16) _Float16 sB[9216];        // 64 chunks x 144 halves
    __shared__ __align__(16) float part2[2][8][276];   // k-split partials

    const int tid  = threadIdx.x;
    const int g    = blockIdx.x & 31;
    const int role = blockIdx.x >> 5;
    const bool isL1 = role >= 4;
    const int q = role & 3;
    const int batch0 = g * 8;
    u64* ring0 = h0ring + (size_t)g * 8192;   // [slot8][q4][j8][hp32]
    u64* ring1 = h1ring + (size_t)g * 8192;
    u32* cflag = cflagsA + (size_t)g * 16;

    const int lane = tid & 63, w = tid >> 6;
    const int mw = w & 3, kh = w >> 2;
    const int bcol = lane & 15, kc = lane >> 4;

    // ---- A-fragment rows: wave mw owns gate mw; tiles ti=0..3 (r12 layout) ----
    const int R0 = mw * 256 + 64 * q + (lane & 15);
    const int R1 = R0 + 16, R2 = R0 + 32, R3 = R0 + 48;

#define DECL_TI(ti) f16x8 A##ti##_0={},A##ti##_1={},A##ti##_2={},A##ti##_3={}, \
                          A##ti##_4={},A##ti##_5={},A##ti##_6={},A##ti##_7={};
    DECL_TI(0) DECL_TI(1) DECL_TI(2) DECL_TI(3)
#undef DECL_TI

    if (isL1) {
#define LDA1(ti,j) { int k_ = (kh*8+(j))*32 + kc*8;                          \
        A##ti##_##j = ld8(k_ < 256 ? Wih1 + (size_t)R##ti*256 + k_           \
                                   : Whh1 + (size_t)R##ti*256 + (k_-256)); }
#define LDA1T(ti) LDA1(ti,0) LDA1(ti,1) LDA1(ti,2) LDA1(ti,3) \
                  LDA1(ti,4) LDA1(ti,5) LDA1(ti,6) LDA1(ti,7)
        LDA1T(0) LDA1T(1) LDA1T(2) LDA1T(3)
#undef LDA1T
#undef LDA1
    } else {
#define LDA0(ti,j) { int k_ = (kh*5+(j))*32 + kc*8;                          \
        A##ti##_##j = ld8(k_ < 64 ? Wih0 + (size_t)R##ti*64 + k_             \
                                  : Whh0 + (size_t)R##ti*256 + (k_-64)); }
#define LDA0T(ti) LDA0(ti,0) LDA0(ti,1) LDA0(ti,2) LDA0(ti,3) LDA0(ti,4)
        LDA0T(0) LDA0T(1) LDA0T(2) LDA0T(3)
#undef LDA0T
#undef LDA0
    }

    // ---- activation duty: thread (lane = h-idx in quadrant, w = batch) ----
    const float* bA = isL1 ? bih1 : bih0;
    const float* bB = isL1 ? bhh1 : bhh0;
    const float bz0 = bA[      64*q + lane] + bB[      64*q + lane];
    const float bz1 = bA[256 + 64*q + lane] + bB[256 + 64*q + lane];
    const float bz2 = bA[512 + 64*q + lane] + bB[512 + 64*q + lane];
    const float bz3 = bA[768 + 64*q + lane] + bB[768 + 64*q + lane];
    float cst = 0.f;

    u32* const sBu = (u32*)sB;
    for (int i = tid; i < 4608; i += 512) sBu[i] = 0;   // incl. pad rows 8-15
    __syncthreads();   // zero-fill complete

    const int n0 = tid & 127;
    const int jj0 = tid >> 7, jj1 = 4 + jj0;
    const size_t qoff = (size_t)((n0 >> 5) << 8) + (n0 & 31);

    // x(s) prefetch register (consumed in stage_old of iter s)
    const bool xduty = (!isL1) && (tid >= 256) && (tid < 384);
    float4 xr = {0, 0, 0, 0};
    if (xduty) {
        int t2 = tid - 256, j = t2 >> 4, c = t2 & 15;
        xr = ((const float4*)(x + (size_t)(batch0 + j) * TT * DD))[c];
    }

#define MST(j, ktb) { const f16x8 Bf = *(const f16x8*)(sB + (((ktb)+(j))*4 + kc)*144 + bcol*8); \
    C0 = __builtin_amdgcn_mfma_f32_16x16x32_f16(A0_##j, Bf, C0, 0,0,0); \
    C1 = __builtin_amdgcn_mfma_f32_16x16x32_f16(A1_##j, Bf, C1, 0,0,0); \
    C2 = __builtin_amdgcn_mfma_f32_16x16x32_f16(A2_##j, Bf, C2, 0,0,0); \
    C3 = __builtin_amdgcn_mfma_f32_16x16x32_f16(A3_##j, Bf, C3, 0,0,0); }

    for (int s = 0; s <= TT + 1; ++s) {
        // L0 computes h0(s) for s<512; L1 computes h1(s-2) for s>=2
        const bool actL = isL1 ? (s >= 2) : (s < TT);

        __syncthreads();                                   // bar_A: sB free

        // ---- issue fresh loads, park in regs ----
        u64 f0 = 0, f1 = 0;
        const u64 *af0 = nullptr, *af1 = nullptr;
        u32 efr = 0;
        if (actL) {
            if (isL1) {   // h1(s-3): slot (s-3)&7, epoch s-2 (s=2 -> 0, memset)
                const u64* b1 = ring1 + (size_t)((s - 3) & 7) * 1024 + qoff;
                af0 = b1 + jj0 * 32; af1 = b1 + jj1 * 32;
                efr = (u32)(s - 2);
            } else {      // h0(s-1): slot (s-1)&7, epoch s (s=0 -> 0, memset)
                const u64* b0 = ring0 + (size_t)((s - 1) & 7) * 1024 + qoff;
                af0 = b0 + jj0 * 32; af1 = b0 + jj1 * 32;
                efr = (u32)s;
            }
            f0 = ld64(af0); f1 = ld64(af1);
        }

        // ---- stage old (L1: h0(s-2), 2 iters aged; L0: x(s) from regs) ----
        if (actL) {
            if (isL1) {
                const u64* b0 = ring0 + (size_t)((s - 2) & 7) * 1024 + qoff;
                const u64 *a0 = b0 + jj0 * 32, *a1 = b0 + jj1 * 32;
                u64 v0 = ld64(a0), v1 = ld64(a1);
                const u32 eo = (u32)(s - 1);
                for (;;) {
                    bool k0 = ((u32)(v0 >> 32) == eo), k1 = ((u32)(v1 >> 32) == eo);
                    if (k0 & k1) break;
                    if (!k0) v0 = ld64(a0);
                    if (!k1) v1 = ld64(a1);
                }
                sBu[(n0 >> 2) * 72 + jj0 * 4 + (n0 & 3)] = (u32)v0;   // cb 0
                sBu[(n0 >> 2) * 72 + jj1 * 4 + (n0 & 3)] = (u32)v1;
            } else if (xduty) {
                int t2 = tid - 256, j = t2 >> 4, c = t2 & 15;
                int bidx = (c >> 1) * 72 + j * 4 + 2 * (c & 1);
                sBu[bidx]     = pkh(xr.x, xr.y);
                sBu[bidx + 1] = pkh(xr.z, xr.w);
            }
        }
        __syncthreads();                                   // bar_B: old staged

        // ---- MFMA old: operand chunks with old data ----
        f32x4 C0 = {0,0,0,0}, C1 = {0,0,0,0}, C2 = {0,0,0,0}, C3 = {0,0,0,0};
        if (actL) {
            if (isL1) {
                if (kh == 0) { MST(0,0) MST(1,0) MST(2,0) MST(3,0)
                               MST(4,0) MST(5,0) MST(6,0) MST(7,0) }
            } else {
                if (kh == 0) { MST(0,0) MST(1,0) }   // x chunks
            }
        }

        // ---- stage fresh: validate parked loads (aged by MFMA_old) ----
        if (actL) {
            for (;;) {
                bool k0 = ((u32)(f0 >> 32) == efr), k1 = ((u32)(f1 >> 32) == efr);
                if (k0 & k1) break;
                if (!k0) f0 = ld64(af0);
                if (!k1) f1 = ld64(af1);
            }
            const int cb = isL1 ? 32 : 8;
            sBu[(cb + (n0 >> 2)) * 72 + jj0 * 4 + (n0 & 3)] = (u32)f0;
            sBu[(cb + (n0 >> 2)) * 72 + jj1 * 4 + (n0 & 3)] = (u32)f1;
        }
        __syncthreads();                                   // bar_C: fresh staged
        if (tid == 0) st32(&cflag[role], (u32)(s + 1));    // staged iter s
        u32 cpre = 0;
        if (actL && lane < 8) cpre = ld32(&cflag[lane]);
        if (xduty && (s + 1 < TT)) {                       // prefetch x(s+1)
            int t2 = tid - 256, j = t2 >> 4, c = t2 & 15;
            xr = ((const float4*)(x + ((size_t)(batch0 + j) * TT + (s + 1)) * DD))[c];
        }

        // ---- MFMA fresh ----
        if (actL) {
            if (isL1) {
                if (kh == 1) { MST(0,8) MST(1,8) MST(2,8) MST(3,8)
                               MST(4,8) MST(5,8) MST(6,8) MST(7,8) }
            } else {
                if (kh == 0) { MST(2,0) MST(3,0) MST(4,0) }
                else         { MST(0,5) MST(1,5) MST(2,5) MST(3,5) MST(4,5) }
            }
            if (bcol < 8) {
                *(f32x4*)&part2[kh][bcol][mw*64 +  0 + kc*4] = C0;
                *(f32x4*)&part2[kh][bcol][mw*64 + 16 + kc*4] = C1;
                *(f32x4*)&part2[kh][bcol][mw*64 + 32 + kc*4] = C2;
                *(f32x4*)&part2[kh][bcol][mw*64 + 48 + kc*4] = C3;
            }
        }
        __syncthreads();                                   // bar_D: part2 ready

        // ---- guard + act + ring store ----
        if (actL) {
            const int tgt = s - 5;   // slot s&7 held h(s-8); latest reader:
            if (tgt > 0) {           // L1 old-stage at iter s-6 -> flag >= s-5
                while (!__all(lane >= 8 || (int)cpre >= tgt)) {
                    __builtin_amdgcn_s_sleep(1);
                    if (lane < 8) cpre = ld32(&cflag[lane]);
                }
            }
            float s0 = part2[0][w][      lane] + part2[1][w][      lane] + bz0;
            float s1 = part2[0][w][ 64 + lane] + part2[1][w][ 64 + lane] + bz1;
            float s2 = part2[0][w][128 + lane] + part2[1][w][128 + lane] + bz2;
            float s3 = part2[0][w][192 + lane] + part2[1][w][192 + lane] + bz3;
            float fi = sigf(s0), ff = sigf(s1), fg = tanhf_(s2), fo = sigf(s3);
            cst = ff * cst + fi * fg;
            float h = fo * tanhf_(cst);
            float hn = __shfl_down(h, 1);
            u32 hw = pkh(h, hn);
            if (!(lane & 1)) {
                // L0: h0(s) epoch s+1 slot s&7; L1: h1(s-2) epoch s-1 slot (s-2)&7
                u64 v = ((u64)(u32)(isL1 ? (s - 1) : (s + 1)) << 32) | (u64)hw;
                u64* dst = (isL1 ? ring1 + (size_t)((s - 2) & 7) * 1024
                                 : ring0 + (size_t)(s & 7) * 1024)
                           + q * 256 + w * 32 + (lane >> 1);
                st64(dst, v);
            }
        }
    }
#undef MST

    // ---- final FC on h1(511): slot 511&7 = 7, epoch 512 = TT ----
    if (isL1 && q == 0) {
        const u32 ef = (u32)TT;
        const u64* b = ring1 + (size_t)7 * 1024 + qoff;
        const u64* a0 = b + jj0 * 32;
        const u64* a1 = b + jj1 * 32;
        u64 v0 = ld64(a0), v1 = ld64(a1);
        for (;;) {
            bool k0 = ((u32)(v0 >> 32) == ef), k1 = ((u32)(v1 >> 32) == ef);
            if (k0 & k1) break;
            if (!k0) v0 = ld64(a0);
            if (!k1) v1 = ld64(a1);
        }
        sBu[jj0 * 128 + n0] = (u32)v0;   // flat [batch][128 u32]
        sBu[jj1 * 128 + n0] = (u32)v1;
        __syncthreads();
        const int j = tid >> 6, l2 = tid & 63;
        const int o = l2 >> 4, kk = l2 & 15;
        float ssum = 0.f;
#pragma unroll
        for (int m = 0; m < 16; ++m) {
            int k = kk * 16 + m;
            ssum += (float)sB[j * 256 + k] * fcW[o * HH + k];
        }
#pragma unroll
        for (int off = 8; off; off >>= 1) ssum += __shfl_down(ssum, off);
        if (kk == 0) out[(batch0 + j) * 4 + o] = ssum + fcb[o];
    }
}

extern "C" void kernel_launch(void* const* d_in, const int* in_sizes, int n_in,
                              void* d_out, int out_size, void* d_ws, size_t ws_size,
                              hipStream_t stream)
{
    (void)in_sizes; (void)n_in; (void)out_size; (void)ws_size;
    const float* x    = (const float*)d_in[0];
    const float* Wih0 = (const float*)d_in[1];
    const float* Whh0 = (const float*)d_in[2];
    const float* bih0 = (const float*)d_in[3];
    const float* bhh0 = (const float*)d_in[4];
    const float* Wih1 = (const float*)d_in[5];
    const float* Whh1 = (const float*)d_in[6];
    const float* bih1 = (const float*)d_in[7];
    const float* bhh1 = (const float*)d_in[8];
    const float* fcW  = (const float*)d_in[9];
    const float* fcb  = (const float*)d_in[10];
    float* out = (float*)d_out;

    // ws: h0ring 2MB (32 grp x 8 slot x 1024 u64) | h1ring 2MB | cflags 2KB
    u64* h0ring = (u64*)d_ws;
    u64* h1ring = (u64*)((char*)d_ws + 2097152);
    u32* cflags = (u32*)((char*)d_ws + 4194304);

    hipMemsetAsync(d_ws, 0, 4194304 + 2048, stream);   // epoch 0 == h(-1)=0

    lstm_persist<<<dim3(256), dim3(512), 0, stream>>>(
        x, Wih0, Whh0, bih0, bhh0, Wih1, Whh1, bih1, bhh1, fcW, fcb, out,
        h0ring, h1ring, cflags);
}